// Round 12
// baseline (16875.848 us; speedup 1.0000x reference)
//
#include <hip/hip_runtime.h>
#include <cstdint>
#include <cstddef>

#define T_SEQ 1024
#define BATCH 64
#define NH 2048
#define HSZ (BATCH * NH)       // halves per h rotation slot
// NINP == 2048 as well

typedef _Float16 half8 __attribute__((ext_vector_type(8)));
typedef _Float16 half4 __attribute__((ext_vector_type(4)));
typedef float f32x4 __attribute__((ext_vector_type(4)));

// ---- LLC-bypass (sc0 sc1) ops: complete at the coherence point (MALL) -----
#define LLC_LD16(dst, base, OFFSTR)                                         \
    asm volatile("global_load_dwordx4 %0, %1, off offset:" OFFSTR " sc0 sc1" \
                 : "=v"(dst) : "v"(base))
#define LLC_ST2(addr, val)                                                   \
    asm volatile("global_store_short %0, %1, off sc0 sc1"                    \
                 :: "v"(addr), "v"(val) : "memory")
#define LLC_ST4(addr, val)                                                   \
    asm volatile("global_store_dword %0, %1, off sc0 sc1"                    \
                 :: "v"(addr), "v"(val) : "memory")
#define LLC_LD4(dst, addr)                                                   \
    asm volatile("global_load_dword %0, %1, off sc0 sc1\n\ts_waitcnt vmcnt(0)" \
                 : "=v"(dst) : "v"(addr))

// Explicit drain: inline-asm VMEM stores are INVISIBLE to hipcc's waitcnt
// insertion (r5/r9 lesson: latent races fire intermittently on graph replay).
__device__ inline void wait_vm0() {
    asm volatile("s_waitcnt vmcnt(0)" ::: "memory");
}

// ---------------- fp32 -> fp16 conversion (vectorized, n % 4 == 0) ----------
__global__ __launch_bounds__(256) void cvt_f32_f16(const float* __restrict__ src,
                                                   _Float16* __restrict__ dst,
                                                   long long n) {
    long long i = ((long long)blockIdx.x * 256 + threadIdx.x) * 4;
    long long stride = (long long)gridDim.x * 256 * 4;
    for (; i < n; i += stride) {
        const float4 v = *(const float4*)(src + i);
        half4 o;
        o[0] = (_Float16)v.x; o[1] = (_Float16)v.y;
        o[2] = (_Float16)v.z; o[3] = (_Float16)v.w;
        *(half4*)(dst + i) = o;
    }
}

// ---------------- fused persistent scan + projection kernel -----------------
// 256 WGs x 512 thr, 1 WG/CU. WG = (group g: 32 b-rows, j-slice idx: 16 cols,
// full K). Per step t:
//   1. quarter-poll: every wave polls the 32 flags[g][mi][kq*32+..] >= t
//      (finer sync: flag certifies 16 rows x 16 cols of h_t).
//   2. recurrence: h frags (LLC bypass) x Wr (LDS, 128KB) -> red reduce ->
//      owners (kq==0) epilogue -> h store (depth-4 rotation) -> drain ->
//      per-owner-wave flag store (t+1).
//   3. fused proj for step t+2: x frags (xh, normal L2-cached, read-only) x
//      Wp fragments held in REGISTERS (96 VGPR/wave, loaded once) ->
//      red2 reduce -> owners' pcN registers. Fills the poll-idle window;
//      eliminates the separate proj_gemm dispatch entirely.
// WAR safety of depth-4 h rotation under quarter-polling: flag(t) of any WG
// <= B(t-1) <= its 4 quarter-waves' polls saw ALL 128 WGs' flags(t-2)
// <= B(t-2) <= every wave finished reading h(t-2). Overwrite target is
// h(t-3) -- strictly older. red/red2 WAR: owners read red after B / red2
// before PROJ-sync2; writers re-write only after the next step's barriers.
__global__ __launch_bounds__(512, 1) void scan_kernel(
    const _Float16* __restrict__ xh,     // [nsteps*64][2048] fp16
    const _Float16* __restrict__ Wr,     // [2][2048][2048] fp16 (W_ih, W_fh)
    const _Float16* __restrict__ Wp,     // [3*2048][2048] fp16 (Wcx|Wix|Wfx)
    _Float16* hslab,                     // [4][64][2048] fp16 rotation
    const float* __restrict__ b_i, const float* __restrict__ b_f,
    float* __restrict__ out,             // d_out: [1024][64][2048] + [64][2048]
    unsigned* flags,                     // [2 g][2 mi][128 idx]
    int t0, int nsteps) {
    extern __shared__ char smem[];
    _Float16* Wlds = (_Float16*)smem;            // 131072 B
    float* red  = (float*)(smem + 131072);       // 12288 B [6][8][64]
    float* red2 = (float*)(smem + 131072 + 12288); // 18432 B [6][12][64]

    const int wg = blockIdx.x;
    const int xcd = wg & 7;
    const int slot = wg >> 3;            // 0..31
    const int g = slot & 1;              // b-group
    const int idx = xcd * 16 + (slot >> 1);   // 0..127, contiguous per XCD
    const int j0 = idx * 16;
    const int b0 = g * 32;

    const int tid = threadIdx.x;
    const int lane = tid & 63;
    const int w = tid >> 6;      // 8 waves
    const int mi = w & 1;        // m-tile (16 rows)
    const int kq = w >> 1;       // k-quarter (512 k)

    // One-time fill of LDS recurrence-weight fragments:
    // frag(gate, fk 0..63, lane l) = W[j0 + (l&15)][fk*32 + (l>>4)*8 ..+8]
    for (int q = 0; q < 16; ++q) {
        int e = q * 512 + tid;            // 0..8191
        int l = e & 63;
        int fk = (e >> 6) & 63;
        int gate = e >> 12;
        const _Float16* src = Wr + ((size_t)gate << 22) +
                              (size_t)(j0 + (l & 15)) * NH + fk * 32 + (l >> 4) * 8;
        *(half8*)(Wlds + ((size_t)(gate * 64 + fk) * 64 + l) * 8) = *(const half8*)src;
    }

    // One-time load of proj-weight fragments into REGISTERS (this wave's
    // k-quarter, 3 mats x 16 kk x 8 halves = 96 VGPRs).
    half8 wpf0[16], wpf1[16], wpf2[16];
#pragma unroll
    for (int u = 0; u < 16; ++u) {
        const size_t coff = (size_t)(j0 + (lane & 15)) * NH + kq * 512 + u * 32 + (lane >> 4) * 8;
        wpf0[u] = *(const half8*)(Wp + coff);
        wpf1[u] = *(const half8*)(Wp + ((size_t)NH * NH) + coff);
        wpf2[u] = *(const half8*)(Wp + 2 * ((size_t)NH * NH) + coff);
    }

    const float bi_s = b_i[j0 + (lane & 15)];
    const float bf_s = b_f[j0 + (lane & 15)];

    // Owner h-carry (plain load: previous dispatch's writes are visible).
    float hprev[4];
    if (kq == 0) {
        const _Float16* hini = hslab + (size_t)(t0 & 3) * HSZ;
#pragma unroll
        for (int r = 0; r < 4; ++r) {
            int b = b0 + mi * 16 + (lane >> 4) * 4 + r;
            hprev[r] = (float)hini[(size_t)b * NH + j0 + (lane & 15)];
        }
    }
    float pcC[4], pixC[4], pfxC[4], pcN[4], pixN[4], pfxN[4];

    __syncthreads();

// proj pass for chunk-relative step TT: all waves MFMA their k-quarter with
// register Wp frags; cross-kq reduce via red2; owners land fp32 results.
#define PROJ_PASS(TT, PC_O, PIX_O, PFX_O)                                     \
    {                                                                         \
        f32x4 a0 = {}, a1 = {}, a2 = {};                                      \
        const _Float16* xr = xh + ((size_t)(TT) * 64 + b0 + mi * 16 +         \
                             (lane & 15)) * NH + kq * 512 + (lane >> 4) * 8;  \
        _Pragma("unroll")                                                     \
        for (int u = 0; u < 16; ++u) {                                        \
            half8 xv = *(const half8*)(xr + u * 32);                          \
            a0 = __builtin_amdgcn_mfma_f32_16x16x32_f16(xv, wpf0[u], a0, 0, 0, 0); \
            a1 = __builtin_amdgcn_mfma_f32_16x16x32_f16(xv, wpf1[u], a1, 0, 0, 0); \
            a2 = __builtin_amdgcn_mfma_f32_16x16x32_f16(xv, wpf2[u], a2, 0, 0, 0); \
        }                                                                     \
        if (kq != 0) {                                                        \
            const int sl = mi * 3 + (kq - 1);                                 \
            _Pragma("unroll")                                                 \
            for (int r = 0; r < 4; ++r) {                                     \
                red2[(sl * 12 + r) * 64 + lane] = a0[r];                      \
                red2[(sl * 12 + 4 + r) * 64 + lane] = a1[r];                  \
                red2[(sl * 12 + 8 + r) * 64 + lane] = a2[r];                  \
            }                                                                 \
        }                                                                     \
        __syncthreads();                                                      \
        if (kq == 0) {                                                        \
            _Pragma("unroll")                                                 \
            for (int p = 0; p < 3; ++p) {                                     \
                const int sl = mi * 3 + p;                                    \
                _Pragma("unroll")                                             \
                for (int r = 0; r < 4; ++r) {                                 \
                    a0[r] += red2[(sl * 12 + r) * 64 + lane];                 \
                    a1[r] += red2[(sl * 12 + 4 + r) * 64 + lane];             \
                    a2[r] += red2[(sl * 12 + 8 + r) * 64 + lane];             \
                }                                                             \
            }                                                                 \
            _Pragma("unroll")                                                 \
            for (int r = 0; r < 4; ++r) {                                     \
                PC_O[r] = a0[r]; PIX_O[r] = a1[r]; PFX_O[r] = a2[r];          \
            }                                                                 \
        }                                                                     \
        __syncthreads();                                                      \
    }

    // Prologue: proj for the first two steps of this chunk.
    PROJ_PASS(0, pcC, pixC, pfxC);
    PROJ_PASS(1, pcN, pixN, pfxN);

    for (int s = 0; s < nsteps; ++s) {
        const int t = t0 + s;
        const _Float16* hin = hslab + (size_t)(t & 3) * HSZ;
        _Float16* hout = hslab + (size_t)((t + 1) & 3) * HSZ;
        const unsigned tv = (unsigned)t;

        // 1. quarter-poll (every wave, its own 32 flags; one cache line).
        {
            const unsigned* fa = flags + (size_t)(g * 2 + mi) * 128 + kq * 32 + (lane & 31);
            while (true) {
                unsigned v;
                LLC_LD4(v, fa);
                if (__all((int)(v >= tv))) break;
                __builtin_amdgcn_s_sleep(1);
            }
        }

        // 2. recurrence: h frags (bypass batch, one wait) x LDS weights.
        half8 afr[16];
        const _Float16* hrow = hin + (size_t)(b0 + mi * 16 + (lane & 15)) * NH +
                               kq * 512 + (lane >> 4) * 8;
        LLC_LD16(afr[0],  hrow, "0");
        LLC_LD16(afr[1],  hrow, "64");
        LLC_LD16(afr[2],  hrow, "128");
        LLC_LD16(afr[3],  hrow, "192");
        LLC_LD16(afr[4],  hrow, "256");
        LLC_LD16(afr[5],  hrow, "320");
        LLC_LD16(afr[6],  hrow, "384");
        LLC_LD16(afr[7],  hrow, "448");
        LLC_LD16(afr[8],  hrow, "512");
        LLC_LD16(afr[9],  hrow, "576");
        LLC_LD16(afr[10], hrow, "640");
        LLC_LD16(afr[11], hrow, "704");
        LLC_LD16(afr[12], hrow, "768");
        LLC_LD16(afr[13], hrow, "832");
        LLC_LD16(afr[14], hrow, "896");
        LLC_LD16(afr[15], hrow, "960");
        wait_vm0();
        __builtin_amdgcn_sched_barrier(0);   // rule #18

        f32x4 ai0 = {}, ai1 = {}, af0 = {}, af1 = {};
#pragma unroll
        for (int u = 0; u < 16; ++u) {
            int fk = kq * 16 + u;
            half8 wi = *(const half8*)(Wlds + ((size_t)fk * 64 + lane) * 8);
            half8 wf = *(const half8*)(Wlds + ((size_t)(64 + fk) * 64 + lane) * 8);
            if (u & 1) {
                ai1 = __builtin_amdgcn_mfma_f32_16x16x32_f16(afr[u], wi, ai1, 0, 0, 0);
                af1 = __builtin_amdgcn_mfma_f32_16x16x32_f16(afr[u], wf, af1, 0, 0, 0);
            } else {
                ai0 = __builtin_amdgcn_mfma_f32_16x16x32_f16(afr[u], wi, ai0, 0, 0, 0);
                af0 = __builtin_amdgcn_mfma_f32_16x16x32_f16(afr[u], wf, af0, 0, 0, 0);
            }
        }
        f32x4 acc_i = ai0 + ai1;
        f32x4 acc_f = af0 + af1;

        if (kq != 0) {   // conflict-free [slot][reg][lane] layout
            const int sl = mi * 3 + (kq - 1);
#pragma unroll
            for (int r = 0; r < 4; ++r) {
                red[(sl * 8 + r) * 64 + lane] = acc_i[r];
                red[(sl * 8 + 4 + r) * 64 + lane] = acc_f[r];
            }
        }
        __syncthreads();   // B

        if (kq == 0) {
#pragma unroll
            for (int p = 0; p < 3; ++p) {
                const int sl = mi * 3 + p;
#pragma unroll
                for (int r = 0; r < 4; ++r) {
                    acc_i[r] += red[(sl * 8 + r) * 64 + lane];
                    acc_f[r] += red[(sl * 8 + 4 + r) * 64 + lane];
                }
            }
            float hn_keep[4];
#pragma unroll
            for (int r = 0; r < 4; ++r) {
                int b = b0 + mi * 16 + (lane >> 4) * 4 + r;
                int j = j0 + (lane & 15);
                float iv = 1.0f / (1.0f + __expf(-(acc_i[r] + pixC[r] + bi_s)));
                float fv = 1.0f / (1.0f + __expf(-(acc_f[r] + pfxC[r] + bf_s)));
                float z = iv * pcC[r] + fv * hprev[r];
                float hn = 1.0f - 2.0f / (__expf(2.0f * z) + 1.0f);   // tanh(z)
                hprev[r] = hn;
                hn_keep[r] = hn;
                _Float16 hn16 = (_Float16)hn;
                LLC_ST2(hout + (size_t)b * NH + j, hn16);
            }
            wait_vm0();   // drain asm h-stores BEFORE publishing the flag
            if (lane == 0)
                LLC_ST4(flags + (size_t)(g * 2 + mi) * 128 + idx, (unsigned)(t + 1));
            // out-stores: off the critical path, normal fire-and-forget.
#pragma unroll
            for (int r = 0; r < 4; ++r) {
                int b = b0 + mi * 16 + (lane >> 4) * 4 + r;
                int j = j0 + (lane & 15);
                out[(size_t)t * (BATCH * NH) + (size_t)b * NH + j] = hn_keep[r];
                if (t == T_SEQ - 1)
                    out[(size_t)T_SEQ * (BATCH * NH) + (size_t)b * NH + j] = hn_keep[r];
            }
            // rotate proj buffers: pcC <- proj(s+1)
#pragma unroll
            for (int r = 0; r < 4; ++r) {
                pcC[r] = pcN[r]; pixC[r] = pixN[r]; pfxC[r] = pfxN[r];
            }
        }

        // 3. fused proj for step s+2 (uniform condition; fills idle window).
        if (s + 2 < nsteps) {
            PROJ_PASS(s + 2, pcN, pixN, pfxN);
        }
    }
}

// ---------------- host launch -----------------------------------------------
extern "C" void kernel_launch(void* const* d_in, const int* in_sizes, int n_in,
                              void* d_out, int out_size, void* d_ws, size_t ws_size,
                              hipStream_t stream) {
    const float* x = (const float*)d_in[0];
    const float* hidden = (const float*)d_in[1];
    const float* W_cx = (const float*)d_in[2];
    const float* W_ih = (const float*)d_in[3];
    const float* W_ix = (const float*)d_in[4];
    const float* W_fh = (const float*)d_in[5];
    const float* W_fx = (const float*)d_in[6];
    const float* b_i = (const float*)d_in[7];
    const float* b_f = (const float*)d_in[8];
    float* out = (float*)d_out;

    char* ws = (char*)d_ws;
    size_t off = 0;
    auto alloc = [&](size_t bytes) {
        char* p = ws + off;
        off += (bytes + 255) & ~(size_t)255;
        return p;
    };
    _Float16* Wp = (_Float16*)alloc((size_t)3 * NH * NH * 2);     // 24 MB
    _Float16* Wr = (_Float16*)alloc((size_t)2 * NH * NH * 2);     // 16 MB
    _Float16* hslab = (_Float16*)alloc((size_t)4 * HSZ * 2);      // 1 MB
    unsigned* flags = (unsigned*)alloc(4096);
    const size_t fixed = off;

    int chunk = 32;
    for (int c = T_SEQ; c >= 32; c >>= 1) {
        size_t need = fixed + (size_t)c * 64 * NH * 2 + 1024;
        if (need <= ws_size) { chunk = c; break; }
    }
    _Float16* xh = (_Float16*)alloc((size_t)chunk * 64 * NH * 2);

    hipMemsetAsync(flags, 0, 4096, stream);

    const long long wsz = (long long)NH * NH;
    cvt_f32_f16<<<2048, 256, 0, stream>>>(W_cx, Wp, wsz);
    cvt_f32_f16<<<2048, 256, 0, stream>>>(W_ix, Wp + wsz, wsz);
    cvt_f32_f16<<<2048, 256, 0, stream>>>(W_fx, Wp + 2 * wsz, wsz);
    cvt_f32_f16<<<2048, 256, 0, stream>>>(W_ih, Wr, wsz);
    cvt_f32_f16<<<2048, 256, 0, stream>>>(W_fh, Wr + wsz, wsz);
    cvt_f32_f16<<<128, 256, 0, stream>>>(hidden, hslab, (long long)BATCH * NH);

    const int nch = T_SEQ / chunk;
    for (int c = 0; c < nch; ++c) {
        const int t0 = c * chunk;
        const int M = chunk * 64;
        cvt_f32_f16<<<2048, 256, 0, stream>>>(x + (size_t)t0 * 64 * NH, xh, (long long)M * NH);
        scan_kernel<<<256, 512, 161792, stream>>>(xh, Wr, Wp, hslab, b_i, b_f,
                                                  out, flags, t0, chunk);
    }
}